// Round 8
// baseline (261.418 us; speedup 1.0000x reference)
//
#include <hip/hip_runtime.h>
#include <hip/hip_bf16.h>

// Problem constants (B=4, T=2048, D=1024, NH=8, NKV=1, HD=128)
#define B_ 4
#define T_ 2048
#define D_ 1024
#define NH_ 8
#define HD_ 128

typedef short short8 __attribute__((ext_vector_type(8)));   // 8 bf16 (4 VGPRs) MFMA frag
typedef float floatx4 __attribute__((ext_vector_type(4)));  // MFMA accumulator

#if __has_builtin(__builtin_amdgcn_exp2f)
#define EXP2F __builtin_amdgcn_exp2f
#else
#define EXP2F exp2f
#endif
#if __has_builtin(__builtin_amdgcn_rcpf)
#define RCPF __builtin_amdgcn_rcpf
#else
__device__ __forceinline__ float RCPF(float x) { return 1.f / x; }
#endif

// async global->LDS 16B copy (m97 lever); LDS dest must be wave-uniform base
// + lane*16B, which the GEMM staging pattern satisfies by construction.
#if __has_builtin(__builtin_amdgcn_global_load_lds)
#define G2L(gp, lp)                                                        \
  __builtin_amdgcn_global_load_lds(                                        \
      (const __attribute__((address_space(1))) unsigned int*)(gp),         \
      (__attribute__((address_space(3))) unsigned int*)(lp), 16, 0, 0)
#else
#define G2L(gp, lp) (*(uint4*)(lp) = *(const uint4*)(gp))
#endif

__device__ __forceinline__ unsigned short f2b(float f) {
  union { float fl; unsigned int i; } v; v.fl = f;
  unsigned int r = v.i + 0x7fffu + ((v.i >> 16) & 1u);  // RNE, non-NaN inputs
  return (unsigned short)(r >> 16);
}
// pack two f32 -> two bf16 (round-to-nearest): low16 = a, high16 = b
__device__ __forceinline__ unsigned int pack_bf16(float a, float b) {
  unsigned int ua = __float_as_uint(a) + 0x8000u;
  unsigned int ub = __float_as_uint(b) + 0x8000u;
  return (ua >> 16) | (ub & 0xffff0000u);
}
__device__ __forceinline__ float blo(unsigned int u) { return __uint_as_float(u << 16); }
__device__ __forceinline__ float bhi(unsigned int u) { return __uint_as_float(u & 0xffff0000u); }

// ---------------------------------------------------------------------------
// One-shot f32 -> bf16 convert of x|Wq|Wk|Wv|Wo into a contiguous bf16 blob.
// ---------------------------------------------------------------------------
__global__ __launch_bounds__(256) void cvt_kernel(
    const float* __restrict__ x,  const float* __restrict__ wq,
    const float* __restrict__ wk, const float* __restrict__ wv,
    const float* __restrict__ wo, unsigned short* __restrict__ dst)
{
  size_t i = ((size_t)blockIdx.x * 256 + threadIdx.x) * 8;
  const float* src; size_t off;
  if      (i <  8388608u) { src = x;  off = i; }
  else if (i <  9437184u) { src = wq; off = i - 8388608u; }
  else if (i <  9568256u) { src = wk; off = i - 9437184u; }
  else if (i <  9699328u) { src = wv; off = i - 9568256u; }
  else                    { src = wo; off = i - 9699328u; }
  float4 a = *(const float4*)(src + off);
  float4 b = *(const float4*)(src + off + 4);
  uint4 o;
  o.x = pack_bf16(a.x, a.y); o.y = pack_bf16(a.z, a.w);
  o.z = pack_bf16(b.x, b.y); o.w = pack_bf16(b.z, b.w);
  *(uint4*)(dst + i) = o;
}

// ---------------------------------------------------------------------------
// 128x128-tile GEMM body, C = A * B^T, K=1024, bf16 in, fp32 accumulate.
// global_load_lds staging into UNPADDED stride-32 LDS (lane-contiguous).
// ---------------------------------------------------------------------------
template <bool C_F32>
__device__ __forceinline__ void gemm_body_1024(
    const unsigned short* __restrict__ Arow0,
    const unsigned short* __restrict__ Btile,
    void* __restrict__ Cb, int ldC)
{
  __shared__ unsigned short As[128 * 32];
  __shared__ unsigned short Bs[128 * 32];
  const int tid = threadIdx.x;
  const int lane = tid & 63;
  const int w = tid >> 6;
  const int wr = w >> 1, wc = w & 1;
  const int l15 = lane & 15, quad = lane >> 4;

  const unsigned short* a_src = Arow0 + (size_t)(tid >> 2) * 1024 + (tid & 3) * 8;
  const unsigned short* b_src = Btile + (size_t)(tid >> 2) * 1024 + (tid & 3) * 8;
  unsigned short* a_dst = &As[(tid >> 2) * 32 + (tid & 3) * 8];
  unsigned short* b_dst = &Bs[(tid >> 2) * 32 + (tid & 3) * 8];

  floatx4 zero = {0.f, 0.f, 0.f, 0.f};
  floatx4 acc[4][4];
#pragma unroll
  for (int i = 0; i < 4; i++)
#pragma unroll
    for (int j = 0; j < 4; j++) acc[i][j] = zero;

  for (int k0 = 0; k0 < 1024; k0 += 32) {
    __syncthreads();
    G2L(a_src + k0,         a_dst);
    G2L(a_src + 65536 + k0, a_dst + 2048);   // +64 rows
    G2L(b_src + k0,         b_dst);
    G2L(b_src + 65536 + k0, b_dst + 2048);
    __syncthreads();                          // drains vmcnt incl. lds-DMA
    short8 af[4], bfr[4];
#pragma unroll
    for (int i = 0; i < 4; i++)
      af[i] = *(const short8*)&As[(wr * 64 + i * 16 + l15) * 32 + quad * 8];
#pragma unroll
    for (int j = 0; j < 4; j++)
      bfr[j] = *(const short8*)&Bs[(wc * 64 + j * 16 + l15) * 32 + quad * 8];
#pragma unroll
    for (int i = 0; i < 4; i++)
#pragma unroll
      for (int j = 0; j < 4; j++)
        acc[i][j] = __builtin_amdgcn_mfma_f32_16x16x32_bf16(af[i], bfr[j], acc[i][j], 0, 0, 0);
  }
  // epilogue: C row = quad*4+reg, col = lane&15 (verified m89/m91 layout)
#pragma unroll
  for (int i = 0; i < 4; i++)
#pragma unroll
    for (int j = 0; j < 4; j++)
#pragma unroll
      for (int r = 0; r < 4; r++) {
        size_t off = (size_t)(wr * 64 + i * 16 + quad * 4 + r) * ldC + wc * 64 + j * 16 + l15;
        if (C_F32) ((float*)Cb)[off] = acc[i][j][r];
        else ((unsigned short*)Cb)[off] = f2b(acc[i][j][r]);
      }
}

__global__ __launch_bounds__(256) void gemm_qkv_kernel(
    const unsigned short* __restrict__ x,
    const unsigned short* __restrict__ Wq,
    const unsigned short* __restrict__ Wk,
    const unsigned short* __restrict__ Wv,
    unsigned short* __restrict__ q,
    unsigned short* __restrict__ k,
    unsigned short* __restrict__ v)
{
  const int bx = blockIdx.x, by = blockIdx.y;
  const unsigned short* Btile;
  unsigned short* C;
  int ldC, col0;
  if (by < 8) { Btile = Wq + (size_t)by * 128 * 1024; C = q; ldC = 1024; col0 = by * 128; }
  else if (by == 8) { Btile = Wk; C = k; ldC = 128; col0 = 0; }
  else { Btile = Wv; C = v; ldC = 128; col0 = 0; }
  gemm_body_1024<false>(x + (size_t)bx * 128 * 1024, Btile,
                        C + (size_t)bx * 128 * ldC + col0, ldC);
}

__global__ __launch_bounds__(256) void gemm_out_kernel(
    const unsigned short* __restrict__ ao,
    const unsigned short* __restrict__ Wo,
    float* __restrict__ out)
{
  const int bx = blockIdx.x, by = blockIdx.y;
  gemm_body_1024<true>(ao + (size_t)bx * 128 * 1024, Wo + (size_t)by * 128 * 1024,
                       out + (size_t)bx * 128 * 1024 + by * 128, 1024);
}

// ---------------------------------------------------------------------------
// prep: fused vtrans (blocks 0..255) + vectorized RoPE (8 pairs/thread).
// q gets gain*(1/sqrt(HD))/SOFTCAP folded in.
// ---------------------------------------------------------------------------
__global__ __launch_bounds__(256) void prep_kernel(
    unsigned short* __restrict__ q,
    unsigned short* __restrict__ k,
    const unsigned short* __restrict__ v,
    unsigned short* __restrict__ vT,
    const float* __restrict__ cosT,
    const float* __restrict__ sinT,
    const float* __restrict__ gain)
{
  __shared__ unsigned short tile[32 * 136];
  const int tid = threadIdx.x;
  if (blockIdx.x < 256) {
    const int b = blockIdx.x >> 6, t0 = (blockIdx.x & 63) * 32;
    for (int u = tid; u < 512; u += 256) {
      int r = u >> 4, c = u & 15;
      *(uint4*)&tile[r * 136 + c * 8] =
          *(const uint4*)(v + ((size_t)(b * T_ + t0 + r)) * 128 + c * 8);
    }
    __syncthreads();
    for (int u = tid; u < 512; u += 256) {
      int d = u >> 2, c = u & 3;
      short8 val;
#pragma unroll
      for (int j = 0; j < 8; j++) val[j] = (short)tile[(c * 8 + j) * 136 + d];
      *(short8*)(vT + ((size_t)(b * 128 + d)) * T_ + t0 + c * 8) = val;
    }
    return;
  }
  int idx = (blockIdx.x - 256) * 256 + tid;   // 0 .. 589823
  unsigned short* ptr;
  size_t base;
  int t, j;
  float g;
  if (idx < 524288) {                         // q: (bt, h, dim-octet j)
    j = idx & 7;
    int h = (idx >> 3) & 7;
    int bt = idx >> 6;
    t = bt & (T_ - 1);
    base = (size_t)bt * 1024 + h * 128 + j * 8;
    ptr = q;
    g = gain[h] * 0.0029462782549439484f;     // (1/sqrt(128))/30
  } else {                                    // k
    int id = idx - 524288;
    j = id & 7;
    int bt = id >> 3;
    t = bt & (T_ - 1);
    base = (size_t)bt * 128 + j * 8;
    ptr = k;
    g = 1.f;
  }
  float4 ca = *(const float4*)&cosT[t * 64 + j * 8];
  float4 cb = *(const float4*)&cosT[t * 64 + j * 8 + 4];
  float4 sa = *(const float4*)&sinT[t * 64 + j * 8];
  float4 sb = *(const float4*)&sinT[t * 64 + j * 8 + 4];
  uint4 lo = *(const uint4*)(ptr + base);
  uint4 hi = *(const uint4*)(ptr + base + 64);
  uint4 olo, ohi;
  {
    float a0 = blo(lo.x), a1 = bhi(lo.x), b0 = blo(hi.x), b1 = bhi(hi.x);
    olo.x = pack_bf16((a0 * ca.x - b0 * sa.x) * g, (a1 * ca.y - b1 * sa.y) * g);
    ohi.x = pack_bf16((a0 * sa.x + b0 * ca.x) * g, (a1 * sa.y + b1 * ca.y) * g);
  }
  {
    float a0 = blo(lo.y), a1 = bhi(lo.y), b0 = blo(hi.y), b1 = bhi(hi.y);
    olo.y = pack_bf16((a0 * ca.z - b0 * sa.z) * g, (a1 * ca.w - b1 * sa.w) * g);
    ohi.y = pack_bf16((a0 * sa.z + b0 * ca.z) * g, (a1 * sa.w + b1 * ca.w) * g);
  }
  {
    float a0 = blo(lo.z), a1 = bhi(lo.z), b0 = blo(hi.z), b1 = bhi(hi.z);
    olo.z = pack_bf16((a0 * cb.x - b0 * sb.x) * g, (a1 * cb.y - b1 * sb.y) * g);
    ohi.z = pack_bf16((a0 * sb.x + b0 * cb.x) * g, (a1 * sb.y + b1 * cb.y) * g);
  }
  {
    float a0 = blo(lo.w), a1 = bhi(lo.w), b0 = blo(hi.w), b1 = bhi(hi.w);
    olo.w = pack_bf16((a0 * cb.z - b0 * sb.z) * g, (a1 * cb.w - b1 * sb.w) * g);
    ohi.w = pack_bf16((a0 * sb.z + b0 * cb.z) * g, (a1 * sb.w + b1 * cb.w) * g);
  }
  *(uint4*)(ptr + base) = olo;
  *(uint4*)(ptr + base + 64) = ohi;
}

// ---------------------------------------------------------------------------
// Flash attention, 512-thread blocks (8 waves) — 2 blocks/CU -> 4 waves/SIMD.
// Fixed cap m=30: p = exp2(-86.5617 * rcp(exp2(2.88539*s) + 1)).
// qblocks of 256 rows (8 total), pair (pr, 7-pr), 4-way key split with
// seg = 2*qblock+2 (exactly divisible) -> every block = 18 iters. K/V tiles
// amortize over 8 waves (1 K-octet + 1 V-octet staged per thread per iter).
// Round-7 lesson: more blocks/CU didn't raise residency; raise waves *inside*
// the block instead. Partials additive; part 3 -> ao, parts 0-2 -> Opart.
// ---------------------------------------------------------------------------
__global__ __launch_bounds__(512) void attn512_kernel(
    const unsigned short* __restrict__ q,
    const unsigned short* __restrict__ k,
    const unsigned short* __restrict__ vT,
    unsigned short* __restrict__ ao,
    unsigned short* __restrict__ Opart,
    float* __restrict__ lbuf)
{
  __shared__ unsigned short Ks[16 * 264];   // [dimgroup d][key*8 + j], 8 pad
  __shared__ unsigned short Vts[128 * 40];  // [dim][key], stride 32+8
  __shared__ unsigned short Pw[8][32 * 40]; // wave-private P[q][key], stride 40

  const int h = blockIdx.y, b = blockIdx.z;
  const int pr = blockIdx.x >> 2, part = blockIdx.x & 3;
  const int tid = threadIdx.x, lane = tid & 63, w = tid >> 6;   // w: 0..7
  const int l15 = lane & 15, quad = lane >> 4;

  // K staging: key = tid>>4 (0..31), dimgroup = tid&15 — one octet/thread
  const unsigned short* ksrc =
      k + (size_t)b * T_ * 128 + (size_t)(tid >> 4) * 128 + (tid & 15) * 8;
  unsigned short* kdst = &Ks[(tid & 15) * 264 + (tid >> 4) * 8];
  // V staging: row = tid>>2 (0..127), col8 = tid&3 — one octet/thread
  const unsigned short* vsrc =
      vT + (size_t)b * 128 * T_ + (size_t)(tid >> 2) * T_ + (tid & 3) * 8;
  unsigned short* vdst = &Vts[(tid >> 2) * 40 + (tid & 3) * 8];

  const floatx4 zero = {0.f, 0.f, 0.f, 0.f};

  for (int pass = 0; pass < 2; pass++) {
    const int qblock = pass ? (7 - pr) : pr;
    const int qbase = qblock * 256;
    const int qw = qbase + w * 32;            // wave's first q-row
    const int seg = 2 * qblock + 2;           // (8j+8)/4
    const int ktBeg = part * seg, ktEnd = ktBeg + seg;

    // Q B-frags for 2 q-subtiles x 4 k-chunks
    short8 qf[2][4];
#pragma unroll
    for (int g = 0; g < 2; g++) {
      const unsigned short* qrow =
          q + ((size_t)(b * T_ + qw + g * 16 + l15) * NH_ + h) * HD_;
#pragma unroll
      for (int c = 0; c < 4; c++) qf[g][c] = *(const short8*)(qrow + c * 32 + quad * 8);
    }

    float l_i[2] = {0.f, 0.f};
    floatx4 acc[8][2];
#pragma unroll
    for (int d = 0; d < 8; d++) { acc[d][0] = zero; acc[d][1] = zero; }

    // prime register staging pipeline at ktBeg
    uint4 kr = *(const uint4*)(ksrc + (size_t)ktBeg * 4096);
    uint4 vr = *(const uint4*)(vsrc + ktBeg * 32);

    for (int kt = ktBeg; kt < ktEnd; kt++) {
      __syncthreads();                 // prev compute done; LDS writable
      *(uint4*)kdst = kr;
      *(uint4*)vdst = vr;
      int ktn = (kt + 1 < ktEnd) ? kt + 1 : kt;          // clamped prefetch
      kr = *(const uint4*)(ksrc + (size_t)ktn * 4096);
      vr = *(const uint4*)(vsrc + ktn * 32);
      __syncthreads();                 // tiles visible; prefetch in flight

      if (kt * 32 <= qw + 31) {        // wave-uniform causal skip
        // S^T = K Q^T: 2 key-subtiles (f) x 2 q-subtiles (g), kf reused over g
        floatx4 st[2][2] = {{zero, zero}, {zero, zero}};
#pragma unroll
        for (int c = 0; c < 4; c++) {
          const int dg = (c * 4 + quad) * 264;
          short8 kf0 = *(const short8*)&Ks[dg + l15 * 8];
          short8 kf1 = *(const short8*)&Ks[dg + (16 + l15) * 8];
          st[0][0] = __builtin_amdgcn_mfma_f32_16x16x32_bf16(kf0, qf[0][c], st[0][0], 0, 0, 0);
          st[0][1] = __builtin_amdgcn_mfma_f32_16x16x32_bf16(kf0, qf[1][c], st[0][1], 0, 0, 0);
          st[1][0] = __builtin_amdgcn_mfma_f32_16x16x32_bf16(kf1, qf[0][c], st[1][0], 0, 0, 0);
          st[1][1] = __builtin_amdgcn_mfma_f32_16x16x32_bf16(kf1, qf[1][c], st[1][1], 0, 0, 0);
        }
        // fused softcap+softmax numerator (fixed m=30) + causal mask
        float rs[2] = {0.f, 0.f};
#pragma unroll
        for (int f = 0; f < 2; f++)
#pragma unroll
          for (int g = 0; g < 2; g++) {
            float pv[4];
            const int qrow = qw + g * 16 + l15;
#pragma unroll
            for (int r = 0; r < 4; r++) {
              float s = st[f][g][r];
              float e = EXP2F(2.8853901f * s);           // e^{2s}
              float u = RCPF(e + 1.f);
              float p = EXP2F(-86.561707f * u);          // exp(30*tanh(s)-30)
              int key = kt * 32 + f * 16 + quad * 4 + r;
              p = (key <= qrow) ? p : 0.f;
              pv[r] = p;
              rs[g] += p;
            }
            uint2 pk;
            pk.x = pack_bf16(pv[0], pv[1]);
            pk.y = pack_bf16(pv[2], pv[3]);
            *(uint2*)&Pw[w][(g * 16 + l15) * 40 + f * 16 + quad * 4] = pk;
          }
#pragma unroll
        for (int g = 0; g < 2; g++) {
          float r2 = rs[g] + __shfl_xor(rs[g], 16);
          l_i[g] += r2 + __shfl_xor(r2, 32);
        }
        // wave-local drain; read P B-frags
        asm volatile("s_waitcnt lgkmcnt(0)" ::: "memory");
        short8 pf0 = *(const short8*)&Pw[w][l15 * 40 + quad * 8];
        short8 pf1 = *(const short8*)&Pw[w][(16 + l15) * 40 + quad * 8];
        // O^T += V^T P^T: vf reused over both q-subtiles
#pragma unroll
        for (int d = 0; d < 8; d++) {
          short8 vf = *(const short8*)&Vts[(d * 16 + l15) * 40 + quad * 8];
          acc[d][0] = __builtin_amdgcn_mfma_f32_16x16x32_bf16(vf, pf0, acc[d][0], 0, 0, 0);
          acc[d][1] = __builtin_amdgcn_mfma_f32_16x16x32_bf16(vf, pf1, acc[d][1], 0, 0, 0);
        }
      }
    }

    // epilogue: O^T D-layout col=l15=q, row=quad*4+r = dim within d-tile
#pragma unroll
    for (int g = 0; g < 2; g++) {
      const size_t rowidx = (size_t)(b * T_ + qw + g * 16 + l15) * NH_ + h;
      unsigned short* dst =
          ((part == 3) ? ao : Opart + (size_t)part * 8388608u) +
          rowidx * HD_ + quad * 4;
#pragma unroll
      for (int d = 0; d < 8; d++) {
        uint2 o;
        o.x = pack_bf16(acc[d][g][0], acc[d][g][1]);
        o.y = pack_bf16(acc[d][g][2], acc[d][g][3]);
        *(uint2*)(dst + d * 16) = o;
      }
      if (quad == 0) lbuf[(size_t)part * 65536u + rowidx] = l_i[g];
    }
  }
}

// ---------------------------------------------------------------------------
// 256-thread fallback attention (round-6 structure), NSPLIT-way split.
// ---------------------------------------------------------------------------
template <int NSPLIT>
__global__ __launch_bounds__(256) void attn_kernel(
    const unsigned short* __restrict__ q,
    const unsigned short* __restrict__ k,
    const unsigned short* __restrict__ vT,
    unsigned short* __restrict__ ao,
    unsigned short* __restrict__ Opart,
    float* __restrict__ lbuf)
{
  __shared__ unsigned short Ks[16 * 264];
  __shared__ unsigned short Vts[128 * 40];
  __shared__ unsigned short Pw[4][32 * 40];

  const int h = blockIdx.y, b = blockIdx.z;
  const int pr   = blockIdx.x / NSPLIT;
  const int part = blockIdx.x % NSPLIT;
  const int tid = threadIdx.x, lane = tid & 63, w = tid >> 6;
  const int l15 = lane & 15, quad = lane >> 4;

  const unsigned short* ksrc =
      k + (size_t)b * T_ * 128 + (size_t)(tid >> 4) * 128 + (tid & 15) * 8;
  unsigned short* kdst0 = &Ks[(tid & 15) * 264 + (tid >> 4) * 8];
  unsigned short* kdst1 = kdst0 + 16 * 8;
  const unsigned short* vsrc =
      vT + (size_t)b * 128 * T_ + (size_t)(tid >> 2) * T_ + (tid & 3) * 8;
  unsigned short* vdst0 = &Vts[(tid >> 2) * 40 + (tid & 3) * 8];
  unsigned short* vdst1 = vdst0 + 64 * 40;

  const floatx4 zero = {0.f, 0.f, 0.f, 0.f};

  for (int pass = 0; pass < 2; pass++) {
    const int qblock = pass ? (15 - pr) : pr;
    const int qbase = qblock * 128;
    const int qw = qbase + w * 32;
    const int seg = (4 * qblock + 4) / NSPLIT;
    const int ktBeg = part * seg, ktEnd = ktBeg + seg;

    short8 qf[2][4];
#pragma unroll
    for (int g = 0; g < 2; g++) {
      const unsigned short* qrow =
          q + ((size_t)(b * T_ + qw + g * 16 + l15) * NH_ + h) * HD_;
#pragma unroll
      for (int c = 0; c < 4; c++) qf[g][c] = *(const short8*)(qrow + c * 32 + quad * 8);
    }

    float l_i[2] = {0.f, 0.f};
    floatx4 acc[8][2];
#pragma unroll
    for (int d = 0; d < 8; d++) { acc[d][0] = zero; acc[d][1] = zero; }

    uint4 kr0 = *(const uint4*)(ksrc + (size_t)ktBeg * 4096);
    uint4 kr1 = *(const uint4*)(ksrc + (size_t)ktBeg * 4096 + 2048);
    uint4 vr0 = *(const uint4*)(vsrc + ktBeg * 32);
    uint4 vr1 = *(const uint4*)(vsrc + (size_t)64 * T_ + ktBeg * 32);

    for (int kt = ktBeg; kt < ktEnd; kt++) {
      __syncthreads();
      *(uint4*)kdst0 = kr0; *(uint4*)kdst1 = kr1;
      *(uint4*)vdst0 = vr0; *(uint4*)vdst1 = vr1;
      int ktn = (kt + 1 < ktEnd) ? kt + 1 : kt;
      kr0 = *(const uint4*)(ksrc + (size_t)ktn * 4096);
      kr1 = *(const uint4*)(ksrc + (size_t)ktn * 4096 + 2048);
      vr0 = *(const uint4*)(vsrc + ktn * 32);
      vr1 = *(const uint4*)(vsrc + (size_t)64 * T_ + ktn * 32);
      __syncthreads();

      if (kt * 32 <= qw + 31) {
        floatx4 st[2][2] = {{zero, zero}, {zero, zero}};
#pragma unroll
        for (int c = 0; c < 4; c++) {
          const int dg = (c * 4 + quad) * 264;
          short8 kf0 = *(const short8*)&Ks[dg + l15 * 8];
          short8 kf1 = *(const short8*)&Ks[dg + (16 + l15) * 8];
          st[0][0] = __builtin_amdgcn_mfma_f32_16x16x32_bf16(kf0, qf[0][c], st[0][0], 0, 0, 0);
          st[0][1] = __builtin_amdgcn_mfma_f32_16x16x32_bf16(kf0, qf[1][c], st[0][1], 0, 0, 0);
          st[1][0] = __builtin_amdgcn_mfma_f32_16x16x32_bf16(kf1, qf[0][c], st[1][0], 0, 0, 0);
          st[1][1] = __builtin_amdgcn_mfma_f32_16x16x32_bf16(kf1, qf[1][c], st[1][1], 0, 0, 0);
        }
        float rs[2] = {0.f, 0.f};
#pragma unroll
        for (int f = 0; f < 2; f++)
#pragma unroll
          for (int g = 0; g < 2; g++) {
            float pv[4];
            const int qrow = qw + g * 16 + l15;
#pragma unroll
            for (int r = 0; r < 4; r++) {
              float s = st[f][g][r];
              float e = EXP2F(2.8853901f * s);
              float u = RCPF(e + 1.f);
              float p = EXP2F(-86.561707f * u);
              int key = kt * 32 + f * 16 + quad * 4 + r;
              p = (key <= qrow) ? p : 0.f;
              pv[r] = p;
              rs[g] += p;
            }
            uint2 pk;
            pk.x = pack_bf16(pv[0], pv[1]);
            pk.y = pack_bf16(pv[2], pv[3]);
            *(uint2*)&Pw[w][(g * 16 + l15) * 40 + f * 16 + quad * 4] = pk;
          }
#pragma unroll
        for (int g = 0; g < 2; g++) {
          float r2 = rs[g] + __shfl_xor(rs[g], 16);
          l_i[g] += r2 + __shfl_xor(r2, 32);
        }
        asm volatile("s_waitcnt lgkmcnt(0)" ::: "memory");
        short8 pf0 = *(const short8*)&Pw[w][l15 * 40 + quad * 8];
        short8 pf1 = *(const short8*)&Pw[w][(16 + l15) * 40 + quad * 8];
#pragma unroll
        for (int d = 0; d < 8; d++) {
          short8 vf = *(const short8*)&Vts[(d * 16 + l15) * 40 + quad * 8];
          acc[d][0] = __builtin_amdgcn_mfma_f32_16x16x32_bf16(vf, pf0, acc[d][0], 0, 0, 0);
          acc[d][1] = __builtin_amdgcn_mfma_f32_16x16x32_bf16(vf, pf1, acc[d][1], 0, 0, 0);
        }
      }
    }

#pragma unroll
    for (int g = 0; g < 2; g++) {
      const size_t rowidx = (size_t)(b * T_ + qw + g * 16 + l15) * NH_ + h;
      if (NSPLIT == 1) {
        float linv = 1.f / l_i[g];
        unsigned short* aop = ao + rowidx * HD_ + quad * 4;
#pragma unroll
        for (int d = 0; d < 8; d++) {
          uint2 o;
          o.x = pack_bf16(acc[d][g][0] * linv, acc[d][g][1] * linv);
          o.y = pack_bf16(acc[d][g][2] * linv, acc[d][g][3] * linv);
          *(uint2*)(aop + d * 16) = o;
        }
      } else {
        unsigned short* dst =
            ((part == NSPLIT - 1) ? ao : Opart + (size_t)part * 8388608u) +
            rowidx * HD_ + quad * 4;
#pragma unroll
        for (int d = 0; d < 8; d++) {
          uint2 o;
          o.x = pack_bf16(acc[d][g][0], acc[d][g][1]);
          o.y = pack_bf16(acc[d][g][2], acc[d][g][3]);
          *(uint2*)(dst + d * 16) = o;
        }
        if (quad == 0) lbuf[(size_t)part * 65536u + rowidx] = l_i[g];
      }
    }
  }
}

// ao = (sum of partials + ao) / (sum of l), 8 bf16 elems per thread
template <int NSPLIT>
__global__ __launch_bounds__(256) void combine_kernel(
    const unsigned short* __restrict__ Opart,
    const float* __restrict__ lbuf,
    unsigned short* __restrict__ ao)
{
  size_t i = ((size_t)blockIdx.x * 256 + threadIdx.x) * 8;
  size_t r = i >> 7;                          // (b*T+t)*NH+h
  float ls = 0.f;
#pragma unroll
  for (int p = 0; p < NSPLIT; p++) ls += lbuf[(size_t)p * 65536u + r];
  float linv = RCPF(ls);
  uint4 c = *(const uint4*)(ao + i);
  float v0 = blo(c.x), v1 = bhi(c.x), v2 = blo(c.y), v3 = bhi(c.y);
  float v4 = blo(c.z), v5 = bhi(c.z), v6 = blo(c.w), v7 = bhi(c.w);
#pragma unroll
  for (int p = 0; p < NSPLIT - 1; p++) {
    uint4 a = *(const uint4*)(Opart + (size_t)p * 8388608u + i);
    v0 += blo(a.x); v1 += bhi(a.x); v2 += blo(a.y); v3 += bhi(a.y);
    v4 += blo(a.z); v5 += bhi(a.z); v6 += blo(a.w); v7 += bhi(a.w);
  }
  uint4 o;
  o.x = pack_bf16(v0 * linv, v1 * linv);
  o.y = pack_bf16(v2 * linv, v3 * linv);
  o.z = pack_bf16(v4 * linv, v5 * linv);
  o.w = pack_bf16(v6 * linv, v7 * linv);
  *(uint4*)(ao + i) = o;
}

extern "C" void kernel_launch(void* const* d_in, const int* in_sizes, int n_in,
                              void* d_out, int out_size, void* d_ws, size_t ws_size,
                              hipStream_t stream) {
  const float* x    = (const float*)d_in[0];
  const float* Wq   = (const float*)d_in[1];
  const float* Wk   = (const float*)d_in[2];
  const float* Wv   = (const float*)d_in[3];
  const float* Wo   = (const float*)d_in[4];
  const float* gain = (const float*)d_in[5];
  const float* cosT = (const float*)d_in[6];
  const float* sinT = (const float*)d_in[7];
  float* out = (float*)d_out;

  unsigned short* ws = (unsigned short*)d_ws;  // elem offsets (bf16)
  unsigned short* blob = ws;                   // x|Wq|Wk|Wv|Wo bf16
  unsigned short* xb  = blob;
  unsigned short* Wqb = blob + 8388608u;
  unsigned short* Wkb = blob + 9437184u;
  unsigned short* Wvb = blob + 9568256u;
  unsigned short* Wob = blob + 9699328u;
  unsigned short* q   = ws + 10747904u;        // 8388608 elems
  unsigned short* kk  = ws + 19136512u;        // 1048576
  unsigned short* v   = ws + 20185088u;        // 1048576
  unsigned short* vT  = ws + 21233664u;        // 1048576
  unsigned short* ao  = xb;                    // alias: xb dead after gemm_qkv
  unsigned short* Opart = ws + 22282240u;      // up to 3 x 8388608 elems
  float* l2 = (float*)((char*)d_ws + 61341696u);   // 2-way: 2 x 65536 f32
  float* l4 = (float*)((char*)d_ws + 94896128u);   // 4-way: 4 x 65536 f32
  const size_t need2 = 61865984ull;
  const size_t need4 = 95944704ull;

  // 0. f32 -> bf16 convert of all GEMM operands
  cvt_kernel<<<5248, 256, 0, stream>>>(x, Wq, Wk, Wv, Wo, blob);
  // 1. fused QKV projection (M=8192, K=1024, N=1024+128+128)
  gemm_qkv_kernel<<<dim3(64, 10), 256, 0, stream>>>(xb, Wqb, Wkb, Wvb, q, kk, v);
  // 2. prep: vtrans (256 blocks) + vectorized RoPE (2304 blocks)
  prep_kernel<<<2560, 256, 0, stream>>>(q, kk, v, vT, cosT, sinT, gain);
  // 3. flash attention + combine
  if (ws_size >= need4) {
    attn512_kernel<<<dim3(16, 8, 4), 512, 0, stream>>>(q, kk, vT, ao, Opart, l4);
    combine_kernel<4><<<4096, 256, 0, stream>>>(Opart, l4, ao);
  } else if (ws_size >= need2) {
    attn_kernel<2><<<dim3(16, 8, 4), 256, 0, stream>>>(q, kk, vT, ao, Opart, l2);
    combine_kernel<2><<<4096, 256, 0, stream>>>(Opart, l2, ao);
  } else {
    attn_kernel<1><<<dim3(8, 8, 4), 256, 0, stream>>>(q, kk, vT, ao, Opart, l2);
  }
  // 4. output projection (bf16 -> f32 out)
  gemm_out_kernel<<<dim3(64, 8), 256, 0, stream>>>(ao, Wob, out);
}

// Round 9
// 233.402 us; speedup vs baseline: 1.1200x; 1.1200x over previous
//
#include <hip/hip_runtime.h>
#include <hip/hip_bf16.h>

// Problem constants (B=4, T=2048, D=1024, NH=8, NKV=1, HD=128)
#define B_ 4
#define T_ 2048
#define D_ 1024
#define NH_ 8
#define HD_ 128

typedef short short8 __attribute__((ext_vector_type(8)));   // 8 bf16 (4 VGPRs) MFMA frag
typedef float floatx4 __attribute__((ext_vector_type(4)));  // MFMA accumulator

#if __has_builtin(__builtin_amdgcn_exp2f)
#define EXP2F __builtin_amdgcn_exp2f
#else
#define EXP2F exp2f
#endif
#if __has_builtin(__builtin_amdgcn_rcpf)
#define RCPF __builtin_amdgcn_rcpf
#else
__device__ __forceinline__ float RCPF(float x) { return 1.f / x; }
#endif

// async global->LDS 16B copy (m97 lever); LDS dest must be wave-uniform base
// + lane*16B, which the GEMM staging pattern satisfies by construction.
#if __has_builtin(__builtin_amdgcn_global_load_lds)
#define G2L(gp, lp)                                                        \
  __builtin_amdgcn_global_load_lds(                                        \
      (const __attribute__((address_space(1))) unsigned int*)(gp),         \
      (__attribute__((address_space(3))) unsigned int*)(lp), 16, 0, 0)
#else
#define G2L(gp, lp) (*(uint4*)(lp) = *(const uint4*)(gp))
#endif

__device__ __forceinline__ unsigned short f2b(float f) {
  union { float fl; unsigned int i; } v; v.fl = f;
  unsigned int r = v.i + 0x7fffu + ((v.i >> 16) & 1u);  // RNE, non-NaN inputs
  return (unsigned short)(r >> 16);
}
// pack two f32 -> two bf16 (round-to-nearest): low16 = a, high16 = b
__device__ __forceinline__ unsigned int pack_bf16(float a, float b) {
  unsigned int ua = __float_as_uint(a) + 0x8000u;
  unsigned int ub = __float_as_uint(b) + 0x8000u;
  return (ua >> 16) | (ub & 0xffff0000u);
}
__device__ __forceinline__ float blo(unsigned int u) { return __uint_as_float(u << 16); }
__device__ __forceinline__ float bhi(unsigned int u) { return __uint_as_float(u & 0xffff0000u); }

// ---------------------------------------------------------------------------
// One-shot f32 -> bf16 convert of x|Wq|Wk|Wv|Wo into a contiguous bf16 blob.
// ---------------------------------------------------------------------------
__global__ __launch_bounds__(256) void cvt_kernel(
    const float* __restrict__ x,  const float* __restrict__ wq,
    const float* __restrict__ wk, const float* __restrict__ wv,
    const float* __restrict__ wo, unsigned short* __restrict__ dst)
{
  size_t i = ((size_t)blockIdx.x * 256 + threadIdx.x) * 8;
  const float* src; size_t off;
  if      (i <  8388608u) { src = x;  off = i; }
  else if (i <  9437184u) { src = wq; off = i - 8388608u; }
  else if (i <  9568256u) { src = wk; off = i - 9437184u; }
  else if (i <  9699328u) { src = wv; off = i - 9568256u; }
  else                    { src = wo; off = i - 9699328u; }
  float4 a = *(const float4*)(src + off);
  float4 b = *(const float4*)(src + off + 4);
  uint4 o;
  o.x = pack_bf16(a.x, a.y); o.y = pack_bf16(a.z, a.w);
  o.z = pack_bf16(b.x, b.y); o.w = pack_bf16(b.z, b.w);
  *(uint4*)(dst + i) = o;
}

// ---------------------------------------------------------------------------
// 128x128-tile GEMM body, C = A * B^T, K=1024, bf16 in, fp32 accumulate.
// global_load_lds staging into UNPADDED stride-32 LDS (lane-contiguous).
// ---------------------------------------------------------------------------
template <bool C_F32>
__device__ __forceinline__ void gemm_body_1024(
    const unsigned short* __restrict__ Arow0,
    const unsigned short* __restrict__ Btile,
    void* __restrict__ Cb, int ldC)
{
  __shared__ unsigned short As[128 * 32];
  __shared__ unsigned short Bs[128 * 32];
  const int tid = threadIdx.x;
  const int lane = tid & 63;
  const int w = tid >> 6;
  const int wr = w >> 1, wc = w & 1;
  const int l15 = lane & 15, quad = lane >> 4;

  const unsigned short* a_src = Arow0 + (size_t)(tid >> 2) * 1024 + (tid & 3) * 8;
  const unsigned short* b_src = Btile + (size_t)(tid >> 2) * 1024 + (tid & 3) * 8;
  unsigned short* a_dst = &As[(tid >> 2) * 32 + (tid & 3) * 8];
  unsigned short* b_dst = &Bs[(tid >> 2) * 32 + (tid & 3) * 8];

  floatx4 zero = {0.f, 0.f, 0.f, 0.f};
  floatx4 acc[4][4];
#pragma unroll
  for (int i = 0; i < 4; i++)
#pragma unroll
    for (int j = 0; j < 4; j++) acc[i][j] = zero;

  for (int k0 = 0; k0 < 1024; k0 += 32) {
    __syncthreads();
    G2L(a_src + k0,         a_dst);
    G2L(a_src + 65536 + k0, a_dst + 2048);   // +64 rows
    G2L(b_src + k0,         b_dst);
    G2L(b_src + 65536 + k0, b_dst + 2048);
    __syncthreads();                          // drains vmcnt incl. lds-DMA
    short8 af[4], bfr[4];
#pragma unroll
    for (int i = 0; i < 4; i++)
      af[i] = *(const short8*)&As[(wr * 64 + i * 16 + l15) * 32 + quad * 8];
#pragma unroll
    for (int j = 0; j < 4; j++)
      bfr[j] = *(const short8*)&Bs[(wc * 64 + j * 16 + l15) * 32 + quad * 8];
#pragma unroll
    for (int i = 0; i < 4; i++)
#pragma unroll
      for (int j = 0; j < 4; j++)
        acc[i][j] = __builtin_amdgcn_mfma_f32_16x16x32_bf16(af[i], bfr[j], acc[i][j], 0, 0, 0);
  }
  // epilogue: C row = quad*4+reg, col = lane&15 (verified m89/m91 layout)
#pragma unroll
  for (int i = 0; i < 4; i++)
#pragma unroll
    for (int j = 0; j < 4; j++)
#pragma unroll
      for (int r = 0; r < 4; r++) {
        size_t off = (size_t)(wr * 64 + i * 16 + quad * 4 + r) * ldC + wc * 64 + j * 16 + l15;
        if (C_F32) ((float*)Cb)[off] = acc[i][j][r];
        else ((unsigned short*)Cb)[off] = f2b(acc[i][j][r]);
      }
}

__global__ __launch_bounds__(256) void gemm_qkv_kernel(
    const unsigned short* __restrict__ x,
    const unsigned short* __restrict__ Wq,
    const unsigned short* __restrict__ Wk,
    const unsigned short* __restrict__ Wv,
    unsigned short* __restrict__ q,
    unsigned short* __restrict__ k,
    unsigned short* __restrict__ v)
{
  const int bx = blockIdx.x, by = blockIdx.y;
  const unsigned short* Btile;
  unsigned short* C;
  int ldC, col0;
  if (by < 8) { Btile = Wq + (size_t)by * 128 * 1024; C = q; ldC = 1024; col0 = by * 128; }
  else if (by == 8) { Btile = Wk; C = k; ldC = 128; col0 = 0; }
  else { Btile = Wv; C = v; ldC = 128; col0 = 0; }
  gemm_body_1024<false>(x + (size_t)bx * 128 * 1024, Btile,
                        C + (size_t)bx * 128 * ldC + col0, ldC);
}

__global__ __launch_bounds__(256) void gemm_out_kernel(
    const unsigned short* __restrict__ ao,
    const unsigned short* __restrict__ Wo,
    float* __restrict__ out)
{
  const int bx = blockIdx.x, by = blockIdx.y;
  gemm_body_1024<true>(ao + (size_t)bx * 128 * 1024, Wo + (size_t)by * 128 * 1024,
                       out + (size_t)bx * 128 * 1024 + by * 128, 1024);
}

// ---------------------------------------------------------------------------
// prep: fused vtrans (blocks 0..255) + vectorized RoPE (8 pairs/thread).
// q gets gain*(1/sqrt(HD))/SOFTCAP folded in.
// ---------------------------------------------------------------------------
__global__ __launch_bounds__(256) void prep_kernel(
    unsigned short* __restrict__ q,
    unsigned short* __restrict__ k,
    const unsigned short* __restrict__ v,
    unsigned short* __restrict__ vT,
    const float* __restrict__ cosT,
    const float* __restrict__ sinT,
    const float* __restrict__ gain)
{
  __shared__ unsigned short tile[32 * 136];
  const int tid = threadIdx.x;
  if (blockIdx.x < 256) {
    const int b = blockIdx.x >> 6, t0 = (blockIdx.x & 63) * 32;
    for (int u = tid; u < 512; u += 256) {
      int r = u >> 4, c = u & 15;
      *(uint4*)&tile[r * 136 + c * 8] =
          *(const uint4*)(v + ((size_t)(b * T_ + t0 + r)) * 128 + c * 8);
    }
    __syncthreads();
    for (int u = tid; u < 512; u += 256) {
      int d = u >> 2, c = u & 3;
      short8 val;
#pragma unroll
      for (int j = 0; j < 8; j++) val[j] = (short)tile[(c * 8 + j) * 136 + d];
      *(short8*)(vT + ((size_t)(b * 128 + d)) * T_ + t0 + c * 8) = val;
    }
    return;
  }
  int idx = (blockIdx.x - 256) * 256 + tid;   // 0 .. 589823
  unsigned short* ptr;
  size_t base;
  int t, j;
  float g;
  if (idx < 524288) {                         // q: (bt, h, dim-octet j)
    j = idx & 7;
    int h = (idx >> 3) & 7;
    int bt = idx >> 6;
    t = bt & (T_ - 1);
    base = (size_t)bt * 1024 + h * 128 + j * 8;
    ptr = q;
    g = gain[h] * 0.0029462782549439484f;     // (1/sqrt(128))/30
  } else {                                    // k
    int id = idx - 524288;
    j = id & 7;
    int bt = id >> 3;
    t = bt & (T_ - 1);
    base = (size_t)bt * 128 + j * 8;
    ptr = k;
    g = 1.f;
  }
  float4 ca = *(const float4*)&cosT[t * 64 + j * 8];
  float4 cb = *(const float4*)&cosT[t * 64 + j * 8 + 4];
  float4 sa = *(const float4*)&sinT[t * 64 + j * 8];
  float4 sb = *(const float4*)&sinT[t * 64 + j * 8 + 4];
  uint4 lo = *(const uint4*)(ptr + base);
  uint4 hi = *(const uint4*)(ptr + base + 64);
  uint4 olo, ohi;
  {
    float a0 = blo(lo.x), a1 = bhi(lo.x), b0 = blo(hi.x), b1 = bhi(hi.x);
    olo.x = pack_bf16((a0 * ca.x - b0 * sa.x) * g, (a1 * ca.y - b1 * sa.y) * g);
    ohi.x = pack_bf16((a0 * sa.x + b0 * ca.x) * g, (a1 * sa.y + b1 * ca.y) * g);
  }
  {
    float a0 = blo(lo.y), a1 = bhi(lo.y), b0 = blo(hi.y), b1 = bhi(hi.y);
    olo.y = pack_bf16((a0 * ca.z - b0 * sa.z) * g, (a1 * ca.w - b1 * sa.w) * g);
    ohi.y = pack_bf16((a0 * sa.z + b0 * ca.z) * g, (a1 * sa.w + b1 * ca.w) * g);
  }
  {
    float a0 = blo(lo.z), a1 = bhi(lo.z), b0 = blo(hi.z), b1 = bhi(hi.z);
    olo.z = pack_bf16((a0 * cb.x - b0 * sb.x) * g, (a1 * cb.y - b1 * sb.y) * g);
    ohi.z = pack_bf16((a0 * sb.x + b0 * cb.x) * g, (a1 * sb.y + b1 * cb.y) * g);
  }
  {
    float a0 = blo(lo.w), a1 = bhi(lo.w), b0 = blo(hi.w), b1 = bhi(hi.w);
    olo.w = pack_bf16((a0 * cb.z - b0 * sb.z) * g, (a1 * cb.w - b1 * sb.w) * g);
    ohi.w = pack_bf16((a0 * sb.z + b0 * cb.z) * g, (a1 * sb.w + b1 * cb.w) * g);
  }
  *(uint4*)(ptr + base) = olo;
  *(uint4*)(ptr + base + 64) = ohi;
}

// ---------------------------------------------------------------------------
// Flash attention, 256-thr (round-6 proven config) + single-barrier
// double-buffered K/V staging + unmasked fast path.
// Fixed cap m=30: p = exp2(-86.5617 * rcp(exp2(2.88539*s) + 1)).
// Pairing (pr, 15-pr) x NSPLIT-way key split -> uniform 34-iter blocks at
// NSPLIT=2 (512 blocks, 2 blocks/CU). Rounds 7/8 showed TLP beyond this
// doesn't materialize; this round halves the barrier drain instead
// (2 -> 1 __syncthreads per k-tile via LDS double-buffering).
// ---------------------------------------------------------------------------
template <int NSPLIT>
__global__ __launch_bounds__(256) void attn_kernel(
    const unsigned short* __restrict__ q,
    const unsigned short* __restrict__ k,
    const unsigned short* __restrict__ vT,
    unsigned short* __restrict__ ao,
    unsigned short* __restrict__ Opart,
    float* __restrict__ lbuf)
{
  __shared__ unsigned short Ks[2][16 * 264];   // [buf][dimgroup d][key*8 + j]
  __shared__ unsigned short Vts[2][128 * 40];  // [buf][dim][key]
  __shared__ unsigned short Pw[4][32 * 40];    // wave-private P[q][key]

  const int h = blockIdx.y, b = blockIdx.z;
  const int pr   = blockIdx.x / NSPLIT;
  const int part = blockIdx.x % NSPLIT;
  const int tid = threadIdx.x, lane = tid & 63, w = tid >> 6;
  const int l15 = lane & 15, quad = lane >> 4;

  // K staging: key = tid>>4 (+16), dimgroup = tid&15
  const unsigned short* ksrc =
      k + (size_t)b * T_ * 128 + (size_t)(tid >> 4) * 128 + (tid & 15) * 8;
  const int koff0 = (tid & 15) * 264 + (tid >> 4) * 8;
  const int koff1 = koff0 + 16 * 8;
  // V staging: row = tid>>2 (+64), col8 = tid&3
  const unsigned short* vsrc =
      vT + (size_t)b * 128 * T_ + (size_t)(tid >> 2) * T_ + (tid & 3) * 8;
  const int voff0 = (tid >> 2) * 40 + (tid & 3) * 8;
  const int voff1 = voff0 + 64 * 40;

  const floatx4 zero = {0.f, 0.f, 0.f, 0.f};

  for (int pass = 0; pass < 2; pass++) {
    const int qblock = pass ? (15 - pr) : pr;
    const int qbase = qblock * 128;
    const int qw = qbase + w * 32;            // wave's first q-row
    const int seg = (4 * qblock + 4) / NSPLIT;
    const int ktBeg = part * seg, ktEnd = ktBeg + seg;

    // Q B-frags for 2 q-subtiles x 4 k-chunks
    short8 qf[2][4];
#pragma unroll
    for (int g = 0; g < 2; g++) {
      const unsigned short* qrow =
          q + ((size_t)(b * T_ + qw + g * 16 + l15) * NH_ + h) * HD_;
#pragma unroll
      for (int c = 0; c < 4; c++) qf[g][c] = *(const short8*)(qrow + c * 32 + quad * 8);
    }

    float l_i[2] = {0.f, 0.f};
    floatx4 acc[8][2];
#pragma unroll
    for (int d = 0; d < 8; d++) { acc[d][0] = zero; acc[d][1] = zero; }

    // pass-start barrier: previous pass/prologue reads done before reuse
    __syncthreads();
    // prologue: stage tile ktBeg into buf[ktBeg&1]
    {
      uint4 kr0 = *(const uint4*)(ksrc + (size_t)ktBeg * 4096);
      uint4 kr1 = *(const uint4*)(ksrc + (size_t)ktBeg * 4096 + 2048);
      uint4 vr0 = *(const uint4*)(vsrc + ktBeg * 32);
      uint4 vr1 = *(const uint4*)(vsrc + (size_t)64 * T_ + ktBeg * 32);
      unsigned short* kb = Ks[ktBeg & 1];
      unsigned short* vb = Vts[ktBeg & 1];
      *(uint4*)(kb + koff0) = kr0; *(uint4*)(kb + koff1) = kr1;
      *(uint4*)(vb + voff0) = vr0; *(uint4*)(vb + voff1) = vr1;
    }

    for (int kt = ktBeg; kt < ktEnd; kt++) {
      // prefetch tile kt+1 into registers (before barrier; vmcnt waits later)
      uint4 kr0, kr1, vr0, vr1;
      const bool more = (kt + 1 < ktEnd);
      if (more) {
        kr0 = *(const uint4*)(ksrc + (size_t)(kt + 1) * 4096);
        kr1 = *(const uint4*)(ksrc + (size_t)(kt + 1) * 4096 + 2048);
        vr0 = *(const uint4*)(vsrc + (kt + 1) * 32);
        vr1 = *(const uint4*)(vsrc + (size_t)64 * T_ + (kt + 1) * 32);
      }
      __syncthreads();                 // publishes buf[kt&1]
      if (more) {                      // stage kt+1 into the other buffer
        unsigned short* kb = Ks[(kt + 1) & 1];
        unsigned short* vb = Vts[(kt + 1) & 1];
        *(uint4*)(kb + koff0) = kr0; *(uint4*)(kb + koff1) = kr1;
        *(uint4*)(vb + voff0) = vr0; *(uint4*)(vb + voff1) = vr1;
      }

      if (kt * 32 <= qw + 31) {        // wave-uniform causal skip
        const unsigned short* KsC = Ks[kt & 1];
        const unsigned short* VtC = Vts[kt & 1];
        // S^T = K Q^T: 2 key-subtiles (f) x 2 q-subtiles (g), kf reused over g
        floatx4 st[2][2] = {{zero, zero}, {zero, zero}};
#pragma unroll
        for (int c = 0; c < 4; c++) {
          const int dg = (c * 4 + quad) * 264;
          short8 kf0 = *(const short8*)&KsC[dg + l15 * 8];
          short8 kf1 = *(const short8*)&KsC[dg + (16 + l15) * 8];
          st[0][0] = __builtin_amdgcn_mfma_f32_16x16x32_bf16(kf0, qf[0][c], st[0][0], 0, 0, 0);
          st[0][1] = __builtin_amdgcn_mfma_f32_16x16x32_bf16(kf0, qf[1][c], st[0][1], 0, 0, 0);
          st[1][0] = __builtin_amdgcn_mfma_f32_16x16x32_bf16(kf1, qf[0][c], st[1][0], 0, 0, 0);
          st[1][1] = __builtin_amdgcn_mfma_f32_16x16x32_bf16(kf1, qf[1][c], st[1][1], 0, 0, 0);
        }
        // fused softcap+softmax numerator (fixed m=30); fast path when the
        // whole 32-key tile is causally visible to all 32 of this wave's rows
        float rs[2] = {0.f, 0.f};
        if (kt * 32 + 31 <= qw) {      // fully unmasked (most iterations)
#pragma unroll
          for (int f = 0; f < 2; f++)
#pragma unroll
            for (int g = 0; g < 2; g++) {
              float pv[4];
#pragma unroll
              for (int r = 0; r < 4; r++) {
                float s = st[f][g][r];
                float e = EXP2F(2.8853901f * s);
                float u = RCPF(e + 1.f);
                float p = EXP2F(-86.561707f * u);
                pv[r] = p;
                rs[g] += p;
              }
              uint2 pk;
              pk.x = pack_bf16(pv[0], pv[1]);
              pk.y = pack_bf16(pv[2], pv[3]);
              *(uint2*)&Pw[w][(g * 16 + l15) * 40 + f * 16 + quad * 4] = pk;
            }
        } else {                       // boundary tile: apply causal mask
#pragma unroll
          for (int f = 0; f < 2; f++)
#pragma unroll
            for (int g = 0; g < 2; g++) {
              float pv[4];
              const int qrow = qw + g * 16 + l15;
#pragma unroll
              for (int r = 0; r < 4; r++) {
                float s = st[f][g][r];
                float e = EXP2F(2.8853901f * s);
                float u = RCPF(e + 1.f);
                float p = EXP2F(-86.561707f * u);
                int key = kt * 32 + f * 16 + quad * 4 + r;
                p = (key <= qrow) ? p : 0.f;
                pv[r] = p;
                rs[g] += p;
              }
              uint2 pk;
              pk.x = pack_bf16(pv[0], pv[1]);
              pk.y = pack_bf16(pv[2], pv[3]);
              *(uint2*)&Pw[w][(g * 16 + l15) * 40 + f * 16 + quad * 4] = pk;
            }
        }
#pragma unroll
        for (int g = 0; g < 2; g++) {
          float r2 = rs[g] + __shfl_xor(rs[g], 16);
          l_i[g] += r2 + __shfl_xor(r2, 32);
        }
        // wave-local drain; read P B-frags
        asm volatile("s_waitcnt lgkmcnt(0)" ::: "memory");
        short8 pf0 = *(const short8*)&Pw[w][l15 * 40 + quad * 8];
        short8 pf1 = *(const short8*)&Pw[w][(16 + l15) * 40 + quad * 8];
        // O^T += V^T P^T: vf reused over both q-subtiles
#pragma unroll
        for (int d = 0; d < 8; d++) {
          short8 vf = *(const short8*)&VtC[(d * 16 + l15) * 40 + quad * 8];
          acc[d][0] = __builtin_amdgcn_mfma_f32_16x16x32_bf16(vf, pf0, acc[d][0], 0, 0, 0);
          acc[d][1] = __builtin_amdgcn_mfma_f32_16x16x32_bf16(vf, pf1, acc[d][1], 0, 0, 0);
        }
      }
    }

    // epilogue: O^T D-layout col=l15=q, row=quad*4+r = dim within d-tile
#pragma unroll
    for (int g = 0; g < 2; g++) {
      const size_t rowidx = (size_t)(b * T_ + qw + g * 16 + l15) * NH_ + h;
      if (NSPLIT == 1) {
        float linv = 1.f / l_i[g];
        unsigned short* aop = ao + rowidx * HD_ + quad * 4;
#pragma unroll
        for (int d = 0; d < 8; d++) {
          uint2 o;
          o.x = pack_bf16(acc[d][g][0] * linv, acc[d][g][1] * linv);
          o.y = pack_bf16(acc[d][g][2] * linv, acc[d][g][3] * linv);
          *(uint2*)(aop + d * 16) = o;
        }
      } else {
        unsigned short* dst =
            ((part == NSPLIT - 1) ? ao : Opart + (size_t)part * 8388608u) +
            rowidx * HD_ + quad * 4;
#pragma unroll
        for (int d = 0; d < 8; d++) {
          uint2 o;
          o.x = pack_bf16(acc[d][g][0], acc[d][g][1]);
          o.y = pack_bf16(acc[d][g][2], acc[d][g][3]);
          *(uint2*)(dst + d * 16) = o;
        }
        if (quad == 0) lbuf[(size_t)part * 65536u + rowidx] = l_i[g];
      }
    }
  }
}

// ao = (sum of partials + ao) / (sum of l), 8 bf16 elems per thread
template <int NSPLIT>
__global__ __launch_bounds__(256) void combine_kernel(
    const unsigned short* __restrict__ Opart,
    const float* __restrict__ lbuf,
    unsigned short* __restrict__ ao)
{
  size_t i = ((size_t)blockIdx.x * 256 + threadIdx.x) * 8;
  size_t r = i >> 7;                          // (b*T+t)*NH+h
  float ls = 0.f;
#pragma unroll
  for (int p = 0; p < NSPLIT; p++) ls += lbuf[(size_t)p * 65536u + r];
  float linv = RCPF(ls);
  uint4 c = *(const uint4*)(ao + i);
  float v0 = blo(c.x), v1 = bhi(c.x), v2 = blo(c.y), v3 = bhi(c.y);
  float v4 = blo(c.z), v5 = bhi(c.z), v6 = blo(c.w), v7 = bhi(c.w);
#pragma unroll
  for (int p = 0; p < NSPLIT - 1; p++) {
    uint4 a = *(const uint4*)(Opart + (size_t)p * 8388608u + i);
    v0 += blo(a.x); v1 += bhi(a.x); v2 += blo(a.y); v3 += bhi(a.y);
    v4 += blo(a.z); v5 += bhi(a.z); v6 += blo(a.w); v7 += bhi(a.w);
  }
  uint4 o;
  o.x = pack_bf16(v0 * linv, v1 * linv);
  o.y = pack_bf16(v2 * linv, v3 * linv);
  o.z = pack_bf16(v4 * linv, v5 * linv);
  o.w = pack_bf16(v6 * linv, v7 * linv);
  *(uint4*)(ao + i) = o;
}

extern "C" void kernel_launch(void* const* d_in, const int* in_sizes, int n_in,
                              void* d_out, int out_size, void* d_ws, size_t ws_size,
                              hipStream_t stream) {
  const float* x    = (const float*)d_in[0];
  const float* Wq   = (const float*)d_in[1];
  const float* Wk   = (const float*)d_in[2];
  const float* Wv   = (const float*)d_in[3];
  const float* Wo   = (const float*)d_in[4];
  const float* gain = (const float*)d_in[5];
  const float* cosT = (const float*)d_in[6];
  const float* sinT = (const float*)d_in[7];
  float* out = (float*)d_out;

  unsigned short* ws = (unsigned short*)d_ws;  // elem offsets (bf16)
  unsigned short* blob = ws;                   // x|Wq|Wk|Wv|Wo bf16
  unsigned short* xb  = blob;
  unsigned short* Wqb = blob + 8388608u;
  unsigned short* Wkb = blob + 9437184u;
  unsigned short* Wvb = blob + 9568256u;
  unsigned short* Wob = blob + 9699328u;
  unsigned short* q   = ws + 10747904u;        // 8388608 elems
  unsigned short* kk  = ws + 19136512u;        // 1048576
  unsigned short* v   = ws + 20185088u;        // 1048576
  unsigned short* vT  = ws + 21233664u;        // 1048576
  unsigned short* ao  = xb;                    // alias: xb dead after gemm_qkv
  unsigned short* Opart = ws + 22282240u;      // 8388608 elems (2-way partial)
  float* l2 = (float*)((char*)d_ws + 61341696u);   // 2 x 65536 f32
  const size_t need2 = 61865984ull;

  // 0. f32 -> bf16 convert of all GEMM operands
  cvt_kernel<<<5248, 256, 0, stream>>>(x, Wq, Wk, Wv, Wo, blob);
  // 1. fused QKV projection (M=8192, K=1024, N=1024+128+128)
  gemm_qkv_kernel<<<dim3(64, 10), 256, 0, stream>>>(xb, Wqb, Wkb, Wvb, q, kk, v);
  // 2. prep: vtrans (256 blocks) + vectorized RoPE (2304 blocks)
  prep_kernel<<<2560, 256, 0, stream>>>(q, kk, v, vT, cosT, sinT, gain);
  // 3. flash attention + combine
  if (ws_size >= need2) {
    attn_kernel<2><<<dim3(16, 8, 4), 256, 0, stream>>>(q, kk, vT, ao, Opart, l2);
    combine_kernel<2><<<4096, 256, 0, stream>>>(Opart, l2, ao);
  } else {
    attn_kernel<1><<<dim3(8, 8, 4), 256, 0, stream>>>(q, kk, vT, ao, Opart, l2);
  }
  // 4. output projection (bf16 -> f32 out)
  gemm_out_kernel<<<dim3(64, 8), 256, 0, stream>>>(ao, Wob, out);
}